// Round 4
// baseline (776.763 us; speedup 1.0000x reference)
//
#include <hip/hip_runtime.h>

static constexpr int T_STEPS = 512;
static constexpr int NBATCH  = 256;
static constexpr int DD      = 128;                         // C = D = K = 128
static constexpr long TND    = (long)T_STEPS * NBATCH * DD; // elems per output tensor

typedef short bf16x8 __attribute__((ext_vector_type(8)));   // 8 bf16 in 4 VGPRs
typedef float f32x4  __attribute__((ext_vector_type(4)));
typedef unsigned u32x4 __attribute__((ext_vector_type(4)));

__device__ inline unsigned short f2bf(float f) {            // RNE fp32 -> bf16
  unsigned u = __builtin_bit_cast(unsigned, f);
  unsigned r = u + 0x7FFFu + ((u >> 16) & 1u);
  return (unsigned short)(r >> 16);
}

__device__ inline bf16x8 pack8(const float* s) {
  bf16x8 v;
#pragma unroll
  for (int i = 0; i < 8; ++i) v[i] = (short)f2bf(s[i]);
  return v;
}

// v_cvt_pk_bf16_f32: D.lo = bf16(lo), D.hi = bf16(hi), RNE (gfx950).
__device__ __forceinline__ unsigned cvtpk_bf16(float lo, float hi) {
  unsigned r;
  asm("v_cvt_pk_bf16_f32 %0, %1, %2" : "=v"(r) : "v"(lo), "v"(hi));
  return r;
}

// ---------------------------------------------------------------------------
// Phase 3: Y[M x 128] = A[M x 128] @ Wy^T + by, with Wy as the A-OPERAND and
// the A-tile rows as the B-operand (A/B frag layouts are identical, m89).
// D[row = k = 16j+4q+r][col = n = m] -> per lane k is CONTIGUOUS -> 8 f32x4
// stores per tile instead of 64 scalar dword stores. Bias = C-init.
// ---------------------------------------------------------------------------
__global__ __launch_bounds__(256) void gemm128_yT(
    const float* __restrict__ A, const float* __restrict__ W,
    const float* __restrict__ bias, float* __restrict__ O, int ntiles) {
  const int lane = threadIdx.x & 63;
  const int wib  = threadIdx.x >> 6;     // wave in block (0..3)
  const int m    = lane & 15;
  const int q    = lane >> 4;

  // Wy A-frags: Wf[j][kq] = W[j*16+m][kq*32 + q*8 .. +7]
  bf16x8 Wf[8][4];
#pragma unroll
  for (int j = 0; j < 8; ++j)
#pragma unroll
    for (int kq = 0; kq < 4; ++kq) {
      const float* p = W + (j * 16 + m) * DD + kq * 32 + q * 8;
      float t[8];
      *(float4*)&t[0] = *(const float4*)p;
      *(float4*)&t[4] = *(const float4*)(p + 4);
      Wf[j][kq] = pack8(t);
    }
  // bias in D-layout: bv4[j][r] = bias[16j + 4q + r]
  f32x4 bv4[8];
#pragma unroll
  for (int j = 0; j < 8; ++j) bv4[j] = *(const f32x4*)(bias + j * 16 + 4 * q);

  const int wglobal = blockIdx.x * 4 + wib;
  const int nwaves  = gridDim.x * 4;
  for (int tile = wglobal; tile < ntiles; tile += nwaves) {
    const long r0 = (long)tile * 16;

    bf16x8 af[4];
#pragma unroll
    for (int kq = 0; kq < 4; ++kq) {
      const float* p = A + (r0 + m) * DD + kq * 32 + q * 8;
      float t[8];
      *(float4*)&t[0] = *(const float4*)p;
      *(float4*)&t[4] = *(const float4*)(p + 4);
      af[kq] = pack8(t);
    }
    f32x4 acc[8];
#pragma unroll
    for (int j = 0; j < 8; ++j)
      acc[j] = __builtin_amdgcn_mfma_f32_16x16x32_bf16(Wf[j][0], af[0], bv4[j], 0, 0, 0);
#pragma unroll
    for (int kq = 1; kq < 4; ++kq)
#pragma unroll
      for (int j = 0; j < 8; ++j)
        acc[j] = __builtin_amdgcn_mfma_f32_16x16x32_bf16(Wf[j][kq], af[kq], acc[j], 0, 0, 0);

    float* op = O + (r0 + m) * DD + 4 * q;
#pragma unroll
    for (int j = 0; j < 8; ++j)
      *(f32x4*)(op + j * 16) = acc[j];
  }
}

// ---------------------------------------------------------------------------
// Phase 1+2 FUSED scan (structure verified R3; registers now FIT):
//   unified-file budget ~436 < 450 no-spill threshold (m08):
//   Wxf+Whf 256 (AGPR) + ring 2x32 + bxv 32 + w 16 + acc 32 + temps.
// Ring is 2-deep; each slot's refill is issued INSIDE the step immediately
// after its pack -> ~1.5 steps (~1000 cy) of load lead, covers LLC/HBM mix.
// h-recurrence: kappa-permuted Wh gather + cvt_pk feedback makes the step's
// D quads directly the next step's B-frags (zero shuffle/LDS/barrier).
// ---------------------------------------------------------------------------
__global__ __launch_bounds__(64, 1) void rnn_scan_fused(
    const float* __restrict__ x,  const float* __restrict__ Wx,
    const float* __restrict__ bx, const float* __restrict__ Wh,
    float* __restrict__ H /* [T][N][128] output: all_h */) {
  const int lane = threadIdx.x & 63;
  const int m = lane & 15;   // batch row within the wave's 16-row group
  const int q = lane >> 4;   // quad

  // Wx A-frags, standard slot k = 32kq + 8q + s
  bf16x8 Wxf[8][4];
#pragma unroll
  for (int j = 0; j < 8; ++j)
#pragma unroll
    for (int kq = 0; kq < 4; ++kq) {
      const float* p = Wx + (j * 16 + m) * DD + kq * 32 + q * 8;
      float t[8];
      *(float4*)&t[0] = *(const float4*)p;
      *(float4*)&t[4] = *(const float4*)(p + 4);
      Wxf[j][kq] = pack8(t);
    }

  // Wh A-frags with the q-dependent kappa gather:
  // s<4 -> Wh[16j+m][32kq + 4q + s]; s>=4 -> Wh[16j+m][32kq + 16 + 4q + (s-4)]
  bf16x8 Whf[8][4];
#pragma unroll
  for (int j = 0; j < 8; ++j)
#pragma unroll
    for (int kq = 0; kq < 4; ++kq) {
      const float* p = Wh + (j * 16 + m) * DD + kq * 32 + 4 * q;
      float t[8];
      *(float4*)&t[0] = *(const float4*)p;
      *(float4*)&t[4] = *(const float4*)(p + 16);
      Whf[j][kq] = pack8(t);
    }

  // bias fragment in the D-layout: bxv[j][r] = bx[16j + 4q + r]
  f32x4 bxv[8];
#pragma unroll
  for (int j = 0; j < 8; ++j) bxv[j] = *(const f32x4*)(bx + j * 16 + 4 * q);

  const long stepN = (long)NBATCH * DD;
  const float* xb = x + (long)(blockIdx.x * 16 + m) * DD + 8 * q;  // B-side x gather
  float*       hb = H + (long)(blockIdx.x * 16 + m) * DD + 4 * q;  // D-side h store

  // h feedback in kappa layout: w[j][hw] = bf16x2(h[m][16j+4q+2hw(+1)]); h_-1=0
  unsigned w[8][2];
#pragma unroll
  for (int j = 0; j < 8; ++j) { w[j][0] = 0u; w[j][1] = 0u; }

  auto pref = [&](f32x4 (&r)[8], int t) {   // raw x row, 8 x float4
    const float* p = xb + (long)t * stepN;
#pragma unroll
    for (int kq = 0; kq < 4; ++kq) {
      r[2 * kq]     = *(const f32x4*)(p + kq * 32);
      r[2 * kq + 1] = *(const f32x4*)(p + kq * 32 + 4);
    }
  };

  // step: pack x_t, immediately refill the slot for t_next, then MFMAs.
  auto step = [&](f32x4 (&r)[8], int t, int tn) {
    bf16x8 xf[4];
#pragma unroll
    for (int kq = 0; kq < 4; ++kq) {
      u32x4 u;
      u[0] = cvtpk_bf16(r[2 * kq][0],     r[2 * kq][1]);
      u[1] = cvtpk_bf16(r[2 * kq][2],     r[2 * kq][3]);
      u[2] = cvtpk_bf16(r[2 * kq + 1][0], r[2 * kq + 1][1]);
      u[3] = cvtpk_bf16(r[2 * kq + 1][2], r[2 * kq + 1][3]);
      xf[kq] = __builtin_bit_cast(bf16x8, u);
    }
    pref(r, tn);   // refill this slot now: ~1.5 steps of lead before next use

    // acc = bx + Wx x_t^T   (independent of h -> fills the pipe)
    f32x4 acc[8];
#pragma unroll
    for (int j = 0; j < 8; ++j)
      acc[j] = __builtin_amdgcn_mfma_f32_16x16x32_bf16(Wxf[j][0], xf[0], bxv[j], 0, 0, 0);
#pragma unroll
    for (int kq = 1; kq < 4; ++kq)
#pragma unroll
      for (int j = 0; j < 8; ++j)
        acc[j] = __builtin_amdgcn_mfma_f32_16x16x32_bf16(Wxf[j][kq], xf[kq], acc[j], 0, 0, 0);
    // acc += Wh h^T  (B-frags are last step's packed D quads — zero movement)
#pragma unroll
    for (int kq = 0; kq < 4; ++kq) {
      u32x4 bw;
      bw[0] = w[2 * kq][0];     bw[1] = w[2 * kq][1];
      bw[2] = w[2 * kq + 1][0]; bw[3] = w[2 * kq + 1][1];
      bf16x8 bf = __builtin_bit_cast(bf16x8, bw);
#pragma unroll
      for (int j = 0; j < 8; ++j)
        acc[j] = __builtin_amdgcn_mfma_f32_16x16x32_bf16(Whf[j][kq], bf, acc[j], 0, 0, 0);
    }
    // relu, repack feedback, store fp32 h (fire-and-forget)
    float* hp = hb + (long)t * stepN;
#pragma unroll
    for (int j = 0; j < 8; ++j) {
      f32x4 hv;
#pragma unroll
      for (int rr = 0; rr < 4; ++rr) hv[rr] = fmaxf(acc[j][rr], 0.f);
      w[j][0] = cvtpk_bf16(hv[0], hv[1]);
      w[j][1] = cvtpk_bf16(hv[2], hv[3]);
      *(f32x4*)(hp + j * 16) = hv;
    }
  };

  f32x4 xA[8], xB[8];   // 2-deep named prefetch ring
  pref(xA, 0); pref(xB, 1);

#pragma unroll 1
  for (int t = 0; t < T_STEPS; t += 2) {
    step(xA, t,     t + 2 < T_STEPS ? t + 2 : T_STEPS - 1);
    step(xB, t + 1, t + 3 < T_STEPS ? t + 3 : T_STEPS - 1);
  }
}

// ---------------------------------------------------------------------------
extern "C" void kernel_launch(void* const* d_in, const int* in_sizes, int n_in,
                              void* d_out, int out_size, void* d_ws, size_t ws_size,
                              hipStream_t stream) {
  const float* x  = (const float*)d_in[0];   // (T,N,C)
  const float* Wx = (const float*)d_in[1];   // (D,C)
  const float* bx = (const float*)d_in[2];   // (D)
  const float* Wh = (const float*)d_in[3];   // (D,D)
  const float* Wy = (const float*)d_in[4];   // (K,D)
  const float* by = (const float*)d_in[5];   // (K)

  float* Y = (float*)d_out;        // all_y: [T][N][K]
  float* H = (float*)d_out + TND;  // all_h: [T][N][D]

  const int ntiles = T_STEPS * NBATCH / 16;  // 8192 row-tiles

  rnn_scan_fused<<<NBATCH / 16, 64, 0, stream>>>(x, Wx, bx, Wh, H);  // x -> all_h
  gemm128_yT<<<512, 256, 0, stream>>>(H, Wy, by, Y, ntiles);         // all_y
}

// Round 6
// 650.006 us; speedup vs baseline: 1.1950x; 1.1950x over previous
//
#include <hip/hip_runtime.h>

static constexpr int T_STEPS = 512;
static constexpr int NBATCH  = 256;
static constexpr int DD      = 128;                         // C = D = K = 128
static constexpr long TND    = (long)T_STEPS * NBATCH * DD; // elems per output tensor

typedef short bf16x8 __attribute__((ext_vector_type(8)));   // 8 bf16 in 4 VGPRs
typedef float f32x4  __attribute__((ext_vector_type(4)));
typedef unsigned u32x4 __attribute__((ext_vector_type(4)));

__device__ inline unsigned short f2bf(float f) {            // RNE fp32 -> bf16
  unsigned u = __builtin_bit_cast(unsigned, f);
  unsigned r = u + 0x7FFFu + ((u >> 16) & 1u);
  return (unsigned short)(r >> 16);
}

__device__ inline bf16x8 pack8(const float* s) {
  bf16x8 v;
#pragma unroll
  for (int i = 0; i < 8; ++i) v[i] = (short)f2bf(s[i]);
  return v;
}

// v_cvt_pk_bf16_f32: D.lo = bf16(lo), D.hi = bf16(hi), RNE (gfx950).
__device__ __forceinline__ unsigned cvtpk_bf16(float lo, float hi) {
  unsigned r;
  asm("v_cvt_pk_bf16_f32 %0, %1, %2" : "=v"(r) : "v"(lo), "v"(hi));
  return r;
}

// ---------------------------------------------------------------------------
// Pre-pass: x (f32, 64MB) -> bf16 (32MB), RNE — bitwise identical to the
// in-step pack it replaces. Output parked in the Y region (64MB), which is
// only overwritten by GEMM-Y after the scan has consumed it (same stream).
// ---------------------------------------------------------------------------
__global__ __launch_bounds__(256) void cvt_x_bf16(
    const float* __restrict__ x, unsigned short* __restrict__ xb, long n8) {
  long i = (long)blockIdx.x * 256 + threadIdx.x;
  const long stride = (long)gridDim.x * 256;
  for (; i < n8; i += stride) {
    const float* p = x + i * 8;
    f32x4 a = *(const f32x4*)p, b = *(const f32x4*)(p + 4);
    u32x4 u;
    u[0] = cvtpk_bf16(a[0], a[1]); u[1] = cvtpk_bf16(a[2], a[3]);
    u[2] = cvtpk_bf16(b[0], b[1]); u[3] = cvtpk_bf16(b[2], b[3]);
    *(u32x4*)(xb + i * 8) = u;
  }
}

// ---------------------------------------------------------------------------
// Phase 3: Y[M x 128] = A[M x 128] @ Wy^T + by, Wy as the A-operand so the
// D-layout gives per-lane contiguous k -> 8 f32x4 stores/tile. Bias = C-init.
// ---------------------------------------------------------------------------
__global__ __launch_bounds__(256) void gemm128_yT(
    const float* __restrict__ A, const float* __restrict__ W,
    const float* __restrict__ bias, float* __restrict__ O, int ntiles) {
  const int lane = threadIdx.x & 63;
  const int wib  = threadIdx.x >> 6;     // wave in block (0..3)
  const int m    = lane & 15;
  const int q    = lane >> 4;

  bf16x8 Wf[8][4];
#pragma unroll
  for (int j = 0; j < 8; ++j)
#pragma unroll
    for (int kq = 0; kq < 4; ++kq) {
      const float* p = W + (j * 16 + m) * DD + kq * 32 + q * 8;
      float t[8];
      *(float4*)&t[0] = *(const float4*)p;
      *(float4*)&t[4] = *(const float4*)(p + 4);
      Wf[j][kq] = pack8(t);
    }
  f32x4 bv4[8];
#pragma unroll
  for (int j = 0; j < 8; ++j) bv4[j] = *(const f32x4*)(bias + j * 16 + 4 * q);

  const int wglobal = blockIdx.x * 4 + wib;
  const int nwaves  = gridDim.x * 4;
  for (int tile = wglobal; tile < ntiles; tile += nwaves) {
    const long r0 = (long)tile * 16;

    bf16x8 af[4];
#pragma unroll
    for (int kq = 0; kq < 4; ++kq) {
      const float* p = A + (r0 + m) * DD + kq * 32 + q * 8;
      float t[8];
      *(float4*)&t[0] = *(const float4*)p;
      *(float4*)&t[4] = *(const float4*)(p + 4);
      af[kq] = pack8(t);
    }
    f32x4 acc[8];
#pragma unroll
    for (int j = 0; j < 8; ++j)
      acc[j] = __builtin_amdgcn_mfma_f32_16x16x32_bf16(Wf[j][0], af[0], bv4[j], 0, 0, 0);
#pragma unroll
    for (int kq = 1; kq < 4; ++kq)
#pragma unroll
      for (int j = 0; j < 8; ++j)
        acc[j] = __builtin_amdgcn_mfma_f32_16x16x32_bf16(Wf[j][kq], af[kq], acc[j], 0, 0, 0);

    float* op = O + (r0 + m) * DD + 4 * q;
#pragma unroll
    for (int j = 0; j < 8; ++j)
      *(f32x4*)(op + j * 16) = acc[j];
  }
}

// ---------------------------------------------------------------------------
// Phase 1+2 FUSED scan, v3: x is PRE-CONVERTED bf16, so the ring slots ARE
// MFMA B-fragments (no per-step pack, 16 regs/slot). 4-deep ring, refilled
// after each step (short live ranges, 1-4 steps of load lead).
// Register budget ~420 < 450 no-spill (m08): Wxf+Whf 256 (AGPR side of the
// unified file) + ring 64 + bxv 32 + w 16 + acc 32 + misc.
// h-recurrence (verified R2-R4): kappa-permuted Wh gather + cvt_pk feedback
// makes the step's D quads directly the next step's B-frags — no shuffle,
// no LDS, no barrier anywhere in the scan.
// ---------------------------------------------------------------------------
__global__ __launch_bounds__(64, 1) void rnn_scan_fused(
    const unsigned short* __restrict__ xbf, const float* __restrict__ Wx,
    const float* __restrict__ bx, const float* __restrict__ Wh,
    float* __restrict__ H /* [T][N][128] output: all_h */) {
  const int lane = threadIdx.x & 63;
  const int m = lane & 15;   // batch row within the wave's 16-row group
  const int q = lane >> 4;   // quad

  // Wx A-frags, standard slot k = 32kq + 8q + s
  bf16x8 Wxf[8][4];
#pragma unroll
  for (int j = 0; j < 8; ++j)
#pragma unroll
    for (int kq = 0; kq < 4; ++kq) {
      const float* p = Wx + (j * 16 + m) * DD + kq * 32 + q * 8;
      float t[8];
      *(float4*)&t[0] = *(const float4*)p;
      *(float4*)&t[4] = *(const float4*)(p + 4);
      Wxf[j][kq] = pack8(t);
    }

  // Wh A-frags with the q-dependent kappa gather:
  // s<4 -> Wh[16j+m][32kq + 4q + s]; s>=4 -> Wh[16j+m][32kq + 16 + 4q + (s-4)]
  bf16x8 Whf[8][4];
#pragma unroll
  for (int j = 0; j < 8; ++j)
#pragma unroll
    for (int kq = 0; kq < 4; ++kq) {
      const float* p = Wh + (j * 16 + m) * DD + kq * 32 + 4 * q;
      float t[8];
      *(float4*)&t[0] = *(const float4*)p;
      *(float4*)&t[4] = *(const float4*)(p + 16);
      Whf[j][kq] = pack8(t);
    }

  // bias fragment in the D-layout: bxv[j][r] = bx[16j + 4q + r]
  f32x4 bxv[8];
#pragma unroll
  for (int j = 0; j < 8; ++j) bxv[j] = *(const f32x4*)(bx + j * 16 + 4 * q);

  const long stepN = (long)NBATCH * DD;
  // lane's x gather base: row = block*16+m, element offset 8q (k=32kq+8q+s)
  const unsigned short* xb = xbf + (long)(blockIdx.x * 16 + m) * DD + 8 * q;
  float* hb = H + (long)(blockIdx.x * 16 + m) * DD + 4 * q;  // D-side h store

  // h feedback in kappa layout: w[j][hw] = bf16x2(h[m][16j+4q+2hw(+1)]); h_-1=0
  unsigned w[8][2];
#pragma unroll
  for (int j = 0; j < 8; ++j) { w[j][0] = 0u; w[j][1] = 0u; }

  auto pref = [&](bf16x8 (&r)[4], int t) {   // 4 x 16B: ready-to-use B-frags
    const unsigned short* p = xb + (long)t * stepN;
#pragma unroll
    for (int kq = 0; kq < 4; ++kq) r[kq] = *(const bf16x8*)(p + 32 * kq);
  };

  auto step = [&](const bf16x8 (&xf)[4], int t) {
    // acc = bx + Wx x_t^T   (independent of h -> fills the pipe while the
    // previous step's feedback chain drains)
    f32x4 acc[8];
#pragma unroll
    for (int j = 0; j < 8; ++j)
      acc[j] = __builtin_amdgcn_mfma_f32_16x16x32_bf16(Wxf[j][0], xf[0], bxv[j], 0, 0, 0);
#pragma unroll
    for (int kq = 1; kq < 4; ++kq)
#pragma unroll
      for (int j = 0; j < 8; ++j)
        acc[j] = __builtin_amdgcn_mfma_f32_16x16x32_bf16(Wxf[j][kq], xf[kq], acc[j], 0, 0, 0);
    // acc += Wh h^T  (B-frags are last step's packed D quads — zero movement)
#pragma unroll
    for (int kq = 0; kq < 4; ++kq) {
      u32x4 bw;
      bw[0] = w[2 * kq][0];     bw[1] = w[2 * kq][1];
      bw[2] = w[2 * kq + 1][0]; bw[3] = w[2 * kq + 1][1];
      bf16x8 bf = __builtin_bit_cast(bf16x8, bw);
#pragma unroll
      for (int j = 0; j < 8; ++j)
        acc[j] = __builtin_amdgcn_mfma_f32_16x16x32_bf16(Whf[j][kq], bf, acc[j], 0, 0, 0);
    }
    // relu, repack feedback, store fp32 h (fire-and-forget)
    float* hp = hb + (long)t * stepN;
#pragma unroll
    for (int j = 0; j < 8; ++j) {
      f32x4 hv;
#pragma unroll
      for (int rr = 0; rr < 4; ++rr) hv[rr] = fmaxf(acc[j][rr], 0.f);
      w[j][0] = cvtpk_bf16(hv[0], hv[1]);
      w[j][1] = cvtpk_bf16(hv[2], hv[3]);
      *(f32x4*)(hp + j * 16) = hv;
    }
  };

  bf16x8 rA[4], rB[4], rC[4], rD[4];   // 4-deep named prefetch ring (64 regs)
  pref(rA, 0); pref(rB, 1); pref(rC, 2); pref(rD, 3);

#pragma unroll 1
  for (int t = 0; t < T_STEPS; t += 4) {
    step(rA, t);     pref(rA, t + 4 < T_STEPS ? t + 4 : T_STEPS - 1);
    step(rB, t + 1); pref(rB, t + 5 < T_STEPS ? t + 5 : T_STEPS - 1);
    step(rC, t + 2); pref(rC, t + 6 < T_STEPS ? t + 6 : T_STEPS - 1);
    step(rD, t + 3); pref(rD, t + 7 < T_STEPS ? t + 7 : T_STEPS - 1);
  }
}

// ---------------------------------------------------------------------------
extern "C" void kernel_launch(void* const* d_in, const int* in_sizes, int n_in,
                              void* d_out, int out_size, void* d_ws, size_t ws_size,
                              hipStream_t stream) {
  const float* x  = (const float*)d_in[0];   // (T,N,C)
  const float* Wx = (const float*)d_in[1];   // (D,C)
  const float* bx = (const float*)d_in[2];   // (D)
  const float* Wh = (const float*)d_in[3];   // (D,D)
  const float* Wy = (const float*)d_in[4];   // (K,D)
  const float* by = (const float*)d_in[5];   // (K)

  float* Y = (float*)d_out;        // all_y: [T][N][K]
  float* H = (float*)d_out + TND;  // all_h: [T][N][D]

  // bf16 x staging lives in the Y region (32MB in 64MB); GEMM-Y overwrites
  // it only after the scan has fully consumed it (same-stream ordering).
  unsigned short* xbf = (unsigned short*)Y;

  const int ntiles = T_STEPS * NBATCH / 16;  // 8192 row-tiles

  cvt_x_bf16<<<2048, 256, 0, stream>>>(x, xbf, TND / 8);               // x -> bf16
  rnn_scan_fused<<<NBATCH / 16, 64, 0, stream>>>(xbf, Wx, bx, Wh, H);  // -> all_h
  gemm128_yT<<<512, 256, 0, stream>>>(H, Wy, by, Y, ntiles);           // -> all_y
}